// Round 3
// baseline (171.376 us; speedup 1.0000x reference)
//
#include <hip/hip_runtime.h>
#include <math.h>

#define NB 1024  // batch

// ---------------------------------------------------------------------------
// K0: transpose x (B, C*H*W=3072) -> xT (3072, B), 64x64 LDS tiles
// ---------------------------------------------------------------------------
__global__ __launch_bounds__(256) void k_transpose(const float* __restrict__ x,
                                                   float* __restrict__ xT) {
  __shared__ float tile[64][65];
  const int c0 = blockIdx.x * 64;   // chw tile
  const int b0 = blockIdx.y * 64;   // batch tile
  const int tx = threadIdx.x & 63;
  const int ty = threadIdx.x >> 6;
#pragma unroll
  for (int r = 0; r < 16; ++r) {
    const int bb = r * 4 + ty;
    tile[bb][tx] = x[(size_t)(b0 + bb) * 3072 + c0 + tx];  // coalesced over chw
  }
  __syncthreads();
#pragma unroll
  for (int r = 0; r < 16; ++r) {
    const int cc = r * 4 + ty;
    xT[(size_t)(c0 + cc) * NB + b0 + tx] = tile[tx][cc];   // coalesced over b
  }
}

// ---------------------------------------------------------------------------
// K1: untied conv1 + bias + relu + 2x2 maxpool
//     xT: (3,32,32,B)  w1: (6,3,28,28,25)  b1: (6,28,28)  h1: (6,14,14,B)
//     Weights staged in LDS (chunk-padded to 28 floats for b128 broadcast
//     reads) — avoids per-thread VMEM broadcast-load storm if the compiler
//     fails to scalarize the block-uniform weight addresses.
// ---------------------------------------------------------------------------
__global__ __launch_bounds__(256) void k_conv1(const float* __restrict__ xT,
                                               const float* __restrict__ w1,
                                               const float* __restrict__ b1,
                                               float* __restrict__ h1) {
  const int pos = blockIdx.x;            // 0..195
  const int ph = pos / 14, pw = pos % 14;
  const int b = blockIdx.y * 256 + threadIdx.x;

  // chunk = o*12 + c*4 + i*2 + j  (72 chunks of 25, padded to 28)
  __shared__ __align__(16) float wL[72 * 28];
  __shared__ float bL[24];
  for (int t = threadIdx.x; t < 72 * 25; t += 256) {
    const int chunk = t / 25, p = t - chunk * 25;
    const int o = chunk / 12, rem = chunk - o * 12;
    const int c = rem >> 2, i = (rem >> 1) & 1, j = rem & 1;
    wL[chunk * 28 + p] =
        w1[((size_t)((o * 3 + c) * 28 + (2 * ph + i)) * 28 + (2 * pw + j)) * 25 + p];
  }
  if (threadIdx.x < 24) {
    const int o = threadIdx.x >> 2, i = (threadIdx.x >> 1) & 1, j = threadIdx.x & 1;
    bL[threadIdx.x] = b1[(size_t)(o * 28 + (2 * ph + i)) * 28 + (2 * pw + j)];
  }
  __syncthreads();

  float acc[6][2][2];
#pragma unroll
  for (int o = 0; o < 6; ++o)
#pragma unroll
    for (int i = 0; i < 2; ++i)
#pragma unroll
      for (int j = 0; j < 2; ++j) acc[o][i][j] = 0.f;

  for (int c = 0; c < 3; ++c) {
    float xw[6][6];
#pragma unroll
    for (int dh = 0; dh < 6; ++dh)
#pragma unroll
      for (int dw = 0; dw < 6; ++dw)
        xw[dh][dw] =
            xT[((size_t)(c * 32 + (2 * ph + dh)) * 32 + (2 * pw + dw)) * NB + b];
#pragma unroll
    for (int o = 0; o < 6; ++o)
#pragma unroll
      for (int i = 0; i < 2; ++i)
#pragma unroll
        for (int j = 0; j < 2; ++j) {
          const float* wp = &wL[((o * 3 + c) * 4 + i * 2 + j) * 28];
#pragma unroll
          for (int p = 0; p < 25; ++p)
            acc[o][i][j] = fmaf(xw[i + p / 5][j + p % 5], wp[p], acc[o][i][j]);
        }
  }

#pragma unroll
  for (int o = 0; o < 6; ++o) {
    float v[2][2];
#pragma unroll
    for (int i = 0; i < 2; ++i)
#pragma unroll
      for (int j = 0; j < 2; ++j)
        v[i][j] = fmaxf(acc[o][i][j] + bL[o * 4 + i * 2 + j], 0.f);
    const float m = fmaxf(fmaxf(v[0][0], v[0][1]), fmaxf(v[1][0], v[1][1]));
    h1[((size_t)(o * 14 + ph) * 14 + pw) * NB + b] = m;
  }
}

// ---------------------------------------------------------------------------
// K2: untied conv2 + bias + relu + 2x2 maxpool
//     h1: (6,14,14,B)  w2: (16,6,10,10,25)  b2: (16,10,10)  h2: (16,5,5,B)
// ---------------------------------------------------------------------------
__global__ __launch_bounds__(256) void k_conv2(const float* __restrict__ h1,
                                               const float* __restrict__ w2,
                                               const float* __restrict__ b2,
                                               float* __restrict__ h2) {
  const int pos = blockIdx.x;            // 0..24
  const int ph = pos / 5, pw = pos - 5 * (pos / 5);
  const int og = blockIdx.y;             // 0..3
  const int b = blockIdx.z * 256 + threadIdx.x;

  // chunk = oo*24 + c*4 + i*2 + j  (96 chunks of 25, padded to 28)
  __shared__ __align__(16) float wL[96 * 28];
  __shared__ float bL[16];
  for (int t = threadIdx.x; t < 96 * 25; t += 256) {
    const int chunk = t / 25, p = t - chunk * 25;
    const int oo = chunk / 24, rem = chunk - oo * 24;
    const int c = rem >> 2, i = (rem >> 1) & 1, j = rem & 1;
    const int o = og * 4 + oo;
    wL[chunk * 28 + p] =
        w2[((size_t)((o * 6 + c) * 10 + (2 * ph + i)) * 10 + (2 * pw + j)) * 25 + p];
  }
  if (threadIdx.x < 16) {
    const int oo = threadIdx.x >> 2, i = (threadIdx.x >> 1) & 1, j = threadIdx.x & 1;
    const int o = og * 4 + oo;
    bL[threadIdx.x] = b2[(size_t)(o * 10 + (2 * ph + i)) * 10 + (2 * pw + j)];
  }
  __syncthreads();

  float acc[4][2][2];
#pragma unroll
  for (int oo = 0; oo < 4; ++oo)
#pragma unroll
    for (int i = 0; i < 2; ++i)
#pragma unroll
      for (int j = 0; j < 2; ++j) acc[oo][i][j] = 0.f;

  for (int c = 0; c < 6; ++c) {
    float xw[6][6];
#pragma unroll
    for (int dh = 0; dh < 6; ++dh)
#pragma unroll
      for (int dw = 0; dw < 6; ++dw)
        xw[dh][dw] =
            h1[((size_t)(c * 14 + (2 * ph + dh)) * 14 + (2 * pw + dw)) * NB + b];
#pragma unroll
    for (int oo = 0; oo < 4; ++oo)
#pragma unroll
      for (int i = 0; i < 2; ++i)
#pragma unroll
        for (int j = 0; j < 2; ++j) {
          const float* wp = &wL[((oo * 6 + c) * 4 + i * 2 + j) * 28];
#pragma unroll
          for (int p = 0; p < 25; ++p)
            acc[oo][i][j] = fmaf(xw[i + p / 5][j + p % 5], wp[p], acc[oo][i][j]);
        }
  }

#pragma unroll
  for (int oo = 0; oo < 4; ++oo) {
    const int o = og * 4 + oo;
    float v[2][2];
#pragma unroll
    for (int i = 0; i < 2; ++i)
#pragma unroll
      for (int j = 0; j < 2; ++j)
        v[i][j] = fmaxf(acc[oo][i][j] + bL[oo * 4 + i * 2 + j], 0.f);
    const float m = fmaxf(fmaxf(v[0][0], v[0][1]), fmaxf(v[1][0], v[1][1]));
    h2[((size_t)(o * 5 + ph) * 5 + pw) * NB + b] = m;
  }
}

// ---------------------------------------------------------------------------
// K3: conv3 == GEMM: h3[o,b] = relu( sum_k w3[o,k] * h2[k,b] + b3[o] ), k=400
//     w3 row staged in LDS; 4 independent acc chains.
// ---------------------------------------------------------------------------
__global__ __launch_bounds__(256) void k_conv3(const float* __restrict__ h2,
                                               const float* __restrict__ w3,
                                               const float* __restrict__ b3,
                                               float* __restrict__ h3) {
  const int o = blockIdx.x;              // 0..119
  const int b = blockIdx.y * 256 + threadIdx.x;
  __shared__ __align__(16) float wL[400];
  for (int t = threadIdx.x; t < 400; t += 256) wL[t] = w3[(size_t)o * 400 + t];
  __syncthreads();

  float a0 = 0.f, a1 = 0.f, a2 = 0.f, a3 = 0.f;
#pragma unroll 8
  for (int k = 0; k < 400; k += 4) {
    a0 = fmaf(h2[(size_t)(k + 0) * NB + b], wL[k + 0], a0);
    a1 = fmaf(h2[(size_t)(k + 1) * NB + b], wL[k + 1], a1);
    a2 = fmaf(h2[(size_t)(k + 2) * NB + b], wL[k + 2], a2);
    a3 = fmaf(h2[(size_t)(k + 3) * NB + b], wL[k + 3], a3);
  }
  h3[(size_t)o * NB + b] = fmaxf((a0 + a1) + (a2 + a3) + b3[o], 0.f);
}

// ---------------------------------------------------------------------------
// K4a: h4[j,b] = relu( dot(h3[:,b], fc2w[j,:]) + fc2b[j] ), j<84
//      grid (16 bgroups, 21 jgroups), block 256 = 64 b x 4 j
// ---------------------------------------------------------------------------
__global__ __launch_bounds__(256) void k_fc2(const float* __restrict__ h3,
                                             const float* __restrict__ fc2w,
                                             const float* __restrict__ fc2b,
                                             float* __restrict__ h4) {
  const int b = blockIdx.x * 64 + (threadIdx.x & 63);
  const int jj = threadIdx.x >> 6;                    // wave-uniform 0..3
  const int j = blockIdx.y * 4 + jj;
  __shared__ __align__(16) float wL[4 * 120];
  for (int t = threadIdx.x; t < 480; t += 256)
    wL[t] = fc2w[(size_t)blockIdx.y * 480 + t];
  __syncthreads();

  const float* __restrict__ wp = &wL[jj * 120];
  float a0 = 0.f, a1 = 0.f;
#pragma unroll
  for (int k = 0; k < 120; k += 2) {
    a0 = fmaf(h3[(size_t)(k + 0) * NB + b], wp[k + 0], a0);
    a1 = fmaf(h3[(size_t)(k + 1) * NB + b], wp[k + 1], a1);
  }
  h4[(size_t)j * NB + b] = fmaxf(a0 + a1 + fc2b[j], 0.f);
}

// ---------------------------------------------------------------------------
// K4b: out[b,i] = dot(h4[:,b], fc3w[i,:]) + fc3b[i], i<10
//      grid (16 bgroups, 3 igroups), block 256 = 64 b x 4 i (i>=10 idle)
// ---------------------------------------------------------------------------
__global__ __launch_bounds__(256) void k_fc3(const float* __restrict__ h4,
                                             const float* __restrict__ fc3w,
                                             const float* __restrict__ fc3b,
                                             float* __restrict__ out) {
  const int b = blockIdx.x * 64 + (threadIdx.x & 63);
  const int ii = threadIdx.x >> 6;                    // wave-uniform 0..3
  const int i = blockIdx.y * 4 + ii;
  __shared__ __align__(16) float wL[4 * 84];
  for (int t = threadIdx.x; t < 336; t += 256) {
    const int gi = blockIdx.y * 336 + t;
    wL[t] = (gi < 840) ? fc3w[gi] : 0.f;
  }
  __syncthreads();

  if (i < 10) {
    const float* __restrict__ wp = &wL[ii * 84];
    float a0 = 0.f, a1 = 0.f;
#pragma unroll
    for (int j = 0; j < 84; j += 2) {
      a0 = fmaf(h4[(size_t)(j + 0) * NB + b], wp[j + 0], a0);
      a1 = fmaf(h4[(size_t)(j + 1) * NB + b], wp[j + 1], a1);
    }
    out[(size_t)b * 10 + i] = a0 + a1 + fc3b[i];
  }
}

// ---------------------------------------------------------------------------
extern "C" void kernel_launch(void* const* d_in, const int* in_sizes, int n_in,
                              void* d_out, int out_size, void* d_ws, size_t ws_size,
                              hipStream_t stream) {
  const float* x    = (const float*)d_in[0];
  const float* w1   = (const float*)d_in[1];
  const float* b1   = (const float*)d_in[2];
  const float* w2   = (const float*)d_in[3];
  const float* b2   = (const float*)d_in[4];
  const float* w3   = (const float*)d_in[5];
  const float* b3   = (const float*)d_in[6];
  const float* fc2w = (const float*)d_in[7];
  const float* fc2b = (const float*)d_in[8];
  const float* fc3w = (const float*)d_in[9];
  const float* fc3b = (const float*)d_in[10];
  float* out = (float*)d_out;

  float* ws = (float*)d_ws;
  float* xT = ws;                         // 3*32*32*1024  = 3,145,728 f
  float* h1 = xT + 3145728;               // 6*14*14*1024  = 1,204,224 f
  float* h2 = h1 + 1204224;               // 16*5*5*1024   =   409,600 f
  float* h3 = h2 + 409600;                // 120*1024      =   122,880 f
  float* h4 = xT;                         // 84*1024 — aliases dead xT region

  k_transpose<<<dim3(48, 16), 256, 0, stream>>>(x, xT);
  k_conv1<<<dim3(196, 4), 256, 0, stream>>>(xT, w1, b1, h1);
  k_conv2<<<dim3(25, 4, 4), 256, 0, stream>>>(h1, w2, b2, h2);
  k_conv3<<<dim3(120, 4), 256, 0, stream>>>(h2, w3, b3, h3);
  k_fc2<<<dim3(16, 21), 256, 0, stream>>>(h3, fc2w, fc2b, h4);
  k_fc3<<<dim3(16, 3), 256, 0, stream>>>(h4, fc3w, fc3b, out);
}